// Round 4
// baseline (375.281 us; speedup 1.0000x reference)
//
#include <hip/hip_runtime.h>

// ---------------------------------------------------------------------------
// B=8, S=4096 (rows = 32768), D=1024, DS=64
// segments: qk 512 (tiles 0-31) | v 256 (32-47) | rel 128 (48-55) | val 64 (56-59)
// outputs (flat fp32): idx_qk 8x64 | idx_v 8x32 | rel_Q 8x128 | rel_K 8x128 | val_w 8x64
// R4: single fused kernel per 16-row tile: K-parallel split-bf16 MFMA proj
// (waves partition K, x loads all in flight up-front), LDS reduction, then
// two-pass segment-softmax agg on LDS A-frags. h never touches HBM.
// ---------------------------------------------------------------------------

typedef short short8 __attribute__((ext_vector_type(8)));   // 8 bf16 = 4 VGPR
typedef float f32x4 __attribute__((ext_vector_type(4)));

__device__ __forceinline__ unsigned short f32_to_bf16(float f) {
  unsigned u = __float_as_uint(f);
  u += 0x7FFF + ((u >> 16) & 1);  // RNE
  return (unsigned short)(u >> 16);
}
__device__ __forceinline__ float bf16_to_f32(unsigned short h) {
  return __uint_as_float(((unsigned)h) << 16);
}
__device__ __forceinline__ void split8(const float4& a0, const float4& a1,
                                       short8& hi, short8& lo) {
  float af[8] = {a0.x, a0.y, a0.z, a0.w, a1.x, a1.y, a1.z, a1.w};
#pragma unroll
  for (int j = 0; j < 8; ++j) {
    unsigned short h = f32_to_bf16(af[j]);
    hi[j] = (short)h;
    lo[j] = (short)f32_to_bf16(af[j] - bf16_to_f32(h));
  }
}
#define MFMA(a, b, c) __builtin_amdgcn_mfma_f32_16x16x32_bf16(a, b, c, 0, 0, 0)

// ---- k_prep: zero wg; split proj_w -> whi/wlo; normalize+split emb -> ehi/elo ----
__global__ __launch_bounds__(256) void k_prep(const float* __restrict__ pw,
                                              const float* __restrict__ emb,
                                              unsigned short* __restrict__ whi,
                                              unsigned short* __restrict__ wlo,
                                              unsigned short* __restrict__ ehi,
                                              unsigned short* __restrict__ elo,
                                              float* __restrict__ wg) {
  int tid = blockIdx.x * 256 + threadIdx.x;
  if (tid < 7680) wg[tid] = 0.f;
  for (int i = tid; i < 65536; i += gridDim.x * 256) {
    float v = pw[i];
    unsigned short h = f32_to_bf16(v);
    whi[i] = h;
    wlo[i] = f32_to_bf16(v - bf16_to_f32(h));
  }
  int wid = tid >> 6, lane = tid & 63;
  int nw = gridDim.x * 4;
  for (int n = wid; n < 960; n += nw) {
    float v = emb[n * 64 + lane];
    float s = v * v;
#pragma unroll
    for (int off = 1; off < 64; off <<= 1) s += __shfl_xor(s, off);
    float vn = v / sqrtf(s);
    unsigned short h = f32_to_bf16(vn);
    ehi[n * 64 + lane] = h;
    elo[n * 64 + lane] = f32_to_bf16(vn - bf16_to_f32(h));
  }
}

// ---- k_main: fused proj + segment-softmax agg for 16 rows per block ----
__global__ __launch_bounds__(256) void k_main(const float* __restrict__ x,
                                              const unsigned short* __restrict__ whi,
                                              const unsigned short* __restrict__ wlo,
                                              const float* __restrict__ pb,
                                              const unsigned short* __restrict__ ehi,
                                              const unsigned short* __restrict__ elo,
                                              const float* __restrict__ imp,
                                              float* __restrict__ wg) {
  __shared__ __align__(16) float cpart[4][16][68];          // K-partial C, padded
  __shared__ __align__(16) unsigned short hsh[16][72];       // h hi (144 B rows)
  __shared__ __align__(16) unsigned short hsl[16][72];       // h lo
  __shared__ float zpart[4][16][4];                          // [wave][row][seg]
  __shared__ float coefL[16][4];                             // imp/Z

  int tid = threadIdx.x, w = tid >> 6, lane = tid & 63;
  int q = lane >> 4, c = lane & 15;
  int row0 = blockIdx.x * 16;
  int b = row0 >> 12;

  // ================= proj phase: wave w owns ksteps ks = w + 4j =================
  f32x4 acc[4];
#pragma unroll
  for (int nt = 0; nt < 4; ++nt) acc[nt] = (f32x4){0.f, 0.f, 0.f, 0.f};

  const float* ap = x + (size_t)(row0 + c) * 1024 + q * 8;
  float4 xa[16];  // all 8 ksteps in flight (16 KB/wave outstanding)
#pragma unroll
  for (int j = 0; j < 8; ++j) {
    xa[2 * j]     = *(const float4*)(ap + (w + 4 * j) * 32);
    xa[2 * j + 1] = *(const float4*)(ap + (w + 4 * j) * 32 + 4);
  }
#pragma unroll
  for (int j = 0; j < 8; ++j) {
    int ks = w + 4 * j;
    short8 bhi[4], blo[4];
#pragma unroll
    for (int nt = 0; nt < 4; ++nt) {
      size_t boff = (size_t)(nt * 16 + c) * 1024 + ks * 32 + q * 8;
      bhi[nt] = *(const short8*)(whi + boff);
      blo[nt] = *(const short8*)(wlo + boff);
    }
    short8 ahi, alo;
    split8(xa[2 * j], xa[2 * j + 1], ahi, alo);
#pragma unroll
    for (int nt = 0; nt < 4; ++nt) {
      acc[nt] = MFMA(ahi, bhi[nt], acc[nt]);
      acc[nt] = MFMA(ahi, blo[nt], acc[nt]);
      acc[nt] = MFMA(alo, bhi[nt], acc[nt]);
    }
  }
  // write K-partials to LDS
#pragma unroll
  for (int nt = 0; nt < 4; ++nt)
#pragma unroll
    for (int r = 0; r < 4; ++r) cpart[w][q * 4 + r][nt * 16 + c] = acc[nt][r];
  __syncthreads();
  // reduce partials, add bias, emit h as hi/lo bf16 into LDS
#pragma unroll
  for (int k = 0; k < 4; ++k) {
    int idx = tid + k * 256;
    int row = idx >> 6, col = idx & 63;
    float v = cpart[0][row][col] + cpart[1][row][col] +
              cpart[2][row][col] + cpart[3][row][col] + pb[col];
    unsigned short h = f32_to_bf16(v);
    hsh[row][col] = h;
    hsl[row][col] = f32_to_bf16(v - bf16_to_f32(h));
  }
  __syncthreads();

  // ================= agg phase: two-pass segment softmax =================
  short8 Ahi[2], Alo[2];
#pragma unroll
  for (int ks = 0; ks < 2; ++ks) {
    Ahi[ks] = *(const short8*)&hsh[c][ks * 32 + q * 8];
    Alo[ks] = *(const short8*)&hsl[c][ks * 32 + q * 8];
  }

  // ---- pass 1: segment Z ----
  f32x4 zacc = (f32x4){0.f, 0.f, 0.f, 0.f};
  int cur_seg = 0;
  for (int i = 0; i < 15; ++i) {
    int nt = w + 4 * i;
    int s = (nt < 32) ? 0 : (nt < 48) ? 1 : (nt < 56) ? 2 : 3;
    if (s != cur_seg) {
#pragma unroll
      for (int r = 0; r < 4; ++r) {
        float v = zacc[r];
        v += __shfl_xor(v, 1); v += __shfl_xor(v, 2);
        v += __shfl_xor(v, 4); v += __shfl_xor(v, 8);
        if (c == 0) zpart[w][q * 4 + r][cur_seg] = v;
        zacc[r] = 0.f;
      }
      cur_seg = s;
    }
    size_t eb = (size_t)(nt * 16 + c) * 64 + q * 8;
    short8 bhi0 = *(const short8*)(ehi + eb), bhi1 = *(const short8*)(ehi + eb + 32);
    short8 blo0 = *(const short8*)(elo + eb), blo1 = *(const short8*)(elo + eb + 32);
    f32x4 l = (f32x4){0.f, 0.f, 0.f, 0.f};
    l = MFMA(Ahi[0], bhi0, l); l = MFMA(Ahi[1], bhi1, l);
    l = MFMA(Ahi[0], blo0, l); l = MFMA(Ahi[1], blo1, l);
    l = MFMA(Alo[0], bhi0, l); l = MFMA(Alo[1], bhi1, l);
#pragma unroll
    for (int r = 0; r < 4; ++r) zacc[r] += __expf(l[r]);
  }
#pragma unroll
  for (int r = 0; r < 4; ++r) {  // final flush (val segment)
    float v = zacc[r];
    v += __shfl_xor(v, 1); v += __shfl_xor(v, 2);
    v += __shfl_xor(v, 4); v += __shfl_xor(v, 8);
    if (c == 0) zpart[w][q * 4 + r][cur_seg] = v;
  }
  __syncthreads();
  if (tid < 64) {  // 64 threads = 16 rows x 4 segs
    int row = tid & 15, sg = tid >> 4;
    float Z = zpart[0][row][sg] + zpart[1][row][sg] + zpart[2][row][sg] + zpart[3][row][sg];
    coefL[row][sg] = imp[row0 + row] / Z;
  }
  __syncthreads();

  // ---- pass 2: weighted exp accumulation -> wg atomics ----
  f32x4 cf;
  int cs2 = -1;
  for (int i = 0; i < 15; ++i) {
    int nt = w + 4 * i;
    int s = (nt < 32) ? 0 : (nt < 48) ? 1 : (nt < 56) ? 2 : 3;
    if (s != cs2) {
#pragma unroll
      for (int r = 0; r < 4; ++r) cf[r] = coefL[q * 4 + r][s];
      cs2 = s;
    }
    size_t eb = (size_t)(nt * 16 + c) * 64 + q * 8;
    short8 bhi0 = *(const short8*)(ehi + eb), bhi1 = *(const short8*)(ehi + eb + 32);
    short8 blo0 = *(const short8*)(elo + eb), blo1 = *(const short8*)(elo + eb + 32);
    f32x4 l = (f32x4){0.f, 0.f, 0.f, 0.f};
    l = MFMA(Ahi[0], bhi0, l); l = MFMA(Ahi[1], bhi1, l);
    l = MFMA(Ahi[0], blo0, l); l = MFMA(Ahi[1], blo1, l);
    l = MFMA(Alo[0], bhi0, l); l = MFMA(Alo[1], bhi1, l);
    float wsum = 0.f;
#pragma unroll
    for (int r = 0; r < 4; ++r) wsum = fmaf(__expf(l[r]), cf[r], wsum);
    wsum += __shfl_xor(wsum, 16);
    wsum += __shfl_xor(wsum, 32);  // lanes sharing col c: sum over all 16 rows
    if (lane < 16) atomicAdd(&wg[b * 960 + nt * 16 + c], wsum);
  }
}

// ---- k_topk: parallel rank-based selection + ballot emission ----
__global__ __launch_bounds__(256) void k_topk(const float* __restrict__ wg,
                                              float* __restrict__ out) {
  __shared__ float vals[512];
  __shared__ int flags[512];
  int blk = blockIdx.x;
  int b = blk >> 2, t = blk & 3;
  int tid = threadIdx.x;
  const int Ns[4] = {512, 256, 128, 64};
  const int Ks[4] = {64, 32, 16, 3};
  const int Off[4] = {0, 512, 768, 896};
  int N = Ns[t], K = Ks[t], off = Off[t];
  for (int n = tid; n < N; n += 256) vals[n] = wg[b * 960 + off + n];
  __syncthreads();
  for (int n = tid; n < N; n += 256) {
    float v = vals[n];
    int rank = 0;
    for (int m = 0; m < N; ++m) {
      float u = vals[m];
      rank += (u > v || (u == v && m < n)) ? 1 : 0;
    }
    flags[n] = (rank < K) ? 1 : 0;
  }
  __syncthreads();
  if (t <= 1) {  // sorted ascending index emission via ballot prefix (wave 0)
    if (tid < 64) {
      int base = 0;
      for (int ch = 0; ch < N; ch += 64) {
        int n = ch + tid;
        int f = flags[n];
        unsigned long long mask = __ballot(f);
        if (f) {
          int pos = base + __popcll(mask & ((1ull << tid) - 1ull));
          if (t == 0) out[b * 64 + pos] = (float)n;
          else out[512 + b * 32 + pos] = (float)n;
        }
        base += __popcll(mask);
      }
    }
  } else if (t == 2) {
    for (int n = tid; n < 128; n += 256) {
      float v = flags[n] ? vals[n] : 0.f;
      out[768 + b * 128 + n] = v;
      out[1792 + b * 128 + n] = v;
    }
  } else {
    for (int n = tid; n < 64; n += 256) {
      float v = flags[n] ? vals[n] : 0.f;
      out[2816 + b * 64 + n] = v;
    }
  }
}

extern "C" void kernel_launch(void* const* d_in, const int* in_sizes, int n_in,
                              void* d_out, int out_size, void* d_ws, size_t ws_size,
                              hipStream_t stream) {
  const float* x   = (const float*)d_in[0];   // 8*4096*1024
  const float* imp = (const float*)d_in[1];   // 8*4096
  const float* pw  = (const float*)d_in[2];   // 64*1024
  const float* pb  = (const float*)d_in[3];   // 64
  const float* emb = (const float*)d_in[4];   // 1216*64
  float* out = (float*)d_out;                 // 3328 floats

  char* ws = (char*)d_ws;
  unsigned short* whi = (unsigned short*)(ws);             // 128 KiB
  unsigned short* wlo = (unsigned short*)(ws + 131072);    // 128 KiB
  unsigned short* ehi = (unsigned short*)(ws + 262144);    // 120 KiB
  unsigned short* elo = (unsigned short*)(ws + 385024);    // 120 KiB
  float*          wg  = (float*)(ws + 507904);             // 30 KiB

  hipLaunchKernelGGL(k_prep, dim3(64), dim3(256), 0, stream, pw, emb, whi, wlo, ehi, elo, wg);
  hipLaunchKernelGGL(k_main, dim3(2048), dim3(256), 0, stream, x, whi, wlo, pb, ehi, elo, imp, wg);
  hipLaunchKernelGGL(k_topk, dim3(32), dim3(256), 0, stream, wg, out);
}